// Round 10
// baseline (1033.023 us; speedup 1.0000x reference)
//
#include <hip/hip_runtime.h>
#include <stdint.h>

#define N_NODES 50000
#define HIDDEN  512
#define N_EDGES 200000

#define BK 32
#define LDP 40   // padded LDS row stride (k_gemm_w only)
#define NBX ((N_NODES + 127) / 128)

typedef __attribute__((ext_vector_type(8)))  short short8;
typedef __attribute__((ext_vector_type(4)))  float floatx4;
typedef __attribute__((ext_vector_type(16))) float floatx16;

__device__ inline float bf2f(ushort u) {
    union { uint32_t u; float f; } v; v.u = ((uint32_t)u) << 16; return v.f;
}
__device__ inline ushort f2bf(float f) {
    union { float f; uint32_t u; } v; v.f = f;
    uint32_t r = v.u + 0x7fffu + ((v.u >> 16) & 1u);   // round-to-nearest-even
    return (ushort)(r >> 16);
}
__device__ inline floatx4 mfma16(short8 a, short8 b, floatx4 c) {
    return __builtin_amdgcn_mfma_f32_16x16x32_bf16(a, b, c, 0, 0, 0);
}
__device__ inline floatx16 mfma32(short8 a, short8 b, floatx16 c) {
    return __builtin_amdgcn_mfma_f32_32x32x16_bf16(a, b, c, 0, 0, 0);
}
// async global->LDS, 16B per lane; lds dest is wave-uniform base + lane*16,
// global src address is PER-LANE (pre-swizzled gather is legal).
__device__ inline void gld16(const void* g, void* l) {
    __builtin_amdgcn_global_load_lds(
        (const __attribute__((address_space(1))) unsigned int*)g,
        (__attribute__((address_space(3))) unsigned int*)l, 16, 0, 0);
}
// inline-asm LDS read, opaque to the compiler's waitcnt pass; pair with explicit
// lgkmcnt(0) + sched_barrier(0) before first use (rule #18).
template<int OFF>
__device__ inline short8 dsr(uint a) {
    short8 r;
    asm volatile("ds_read_b128 %0, %1 offset:%2" : "=v"(r) : "v"(a), "n"(OFF));
    return r;
}
// inputs is arange(N_NODES); if harness kept int64, the int32 view is [0,0,1,0,2,0,...]
__device__ inline bool idx_is64(const int* __restrict__ inputs) {
    return inputs[1] == 0 && inputs[2] == 1;
}

// x = bf16(emb[inputs]) : 8 f32 -> 8 bf16 per thread
__global__ void k_gather(const int* __restrict__ inputs, const float* __restrict__ emb,
                         ushort* __restrict__ xb) {
    bool is64 = idx_is64(inputs);
    int t = blockIdx.x * blockDim.x + threadIdx.x;   // N_NODES*64 threads
    int row = t >> 6, s8 = (t & 63) << 3;
    if (row >= N_NODES) return;
    int srow = is64 ? inputs[2 * row] : inputs[row];
    srow = srow < 0 ? 0 : (srow >= N_NODES ? N_NODES - 1 : srow);
    const float* src = emb + (size_t)srow * HIDDEN + s8;
    float4 v0 = *(const float4*)(src);
    float4 v1 = *(const float4*)(src + 4);
    ushort o[8] = { f2bf(v0.x), f2bf(v0.y), f2bf(v0.z), f2bf(v0.w),
                    f2bf(v1.x), f2bf(v1.y), f2bf(v1.z), f2bf(v1.w) };
    *(uint4*)(xb + (size_t)row * HIDDEN + s8) = *(uint4*)o;
}

// generic f32 -> bf16 (8/thread), row-major preserved
__global__ void k_cvt8(const float* __restrict__ src, ushort* __restrict__ dst, int n) {
    int t = blockIdx.x * blockDim.x + threadIdx.x;
    int base = t * 8;
    if (base >= n) return;
    float4 v0 = *(const float4*)(src + base);
    float4 v1 = *(const float4*)(src + base + 4);
    ushort o[8] = { f2bf(v0.x), f2bf(v0.y), f2bf(v0.z), f2bf(v0.w),
                    f2bf(v1.x), f2bf(v1.y), f2bf(v1.z), f2bf(v1.w) };
    *(uint4*)(dst + base) = *(uint4*)o;
}

// Fragment-major weight layout for mfma_32x32x16_bf16 B operand:
// element (grow in [0,1536), k in [0,512)):
//   g = grow>>9, col = grow&511, cb = col>>5, lanelo = col&31,
//   kk = k>>4, hi = (k>>3)&1, j = k&7, lane = lanelo + hi*32
//   idx = (((g*16 + cb)*32 + kk)*64 + lane)*8 + j
// -> each (g,cb,kk) frag is a contiguous 1KB panel; wave load = base + lane*16.
__device__ inline size_t wf_index(int grow, int k) {
    int g3 = grow >> 9, gcol = grow & 511;
    int cb = gcol >> 5, llo = gcol & 31;
    int kk = k >> 4, hi = (k >> 3) & 1, jj = k & 7;
    return ((((size_t)g3 * 16 + cb) * 32 + kk) * 64 + llo + hi * 32) * 8 + jj;
}

// Wc[l][g][k] = sum_j wih[g][j] * W[l][k][j]  (combined gi weights), written frag-major.
// A = WihB [1536][512] contig-j ; B = Wb[l] [512][512] contig-j ; M=1536,N=512,K=512.
__global__ __launch_bounds__(256) void k_gemm_w(const ushort* __restrict__ Aw,
                                                const ushort* __restrict__ Bw,
                                                ushort* __restrict__ Cw) {
    __shared__ ushort As[128][LDP];
    __shared__ ushort Bs[128][LDP];
    const int l = blockIdx.z;
    const ushort* Bp = Bw + (size_t)l * HIDDEN * HIDDEN;
    ushort* Cp = Cw + (size_t)l * 3 * HIDDEN * HIDDEN;
    const int n0 = blockIdx.x * 128, c0 = blockIdx.y * 128;
    const int t = threadIdx.x;
    const int wave = t >> 6, lane = t & 63;
    const int wm = (wave >> 1) << 6, wn = (wave & 1) << 6;
    const int fr = lane & 15, fk = (lane >> 4) << 3;
    const int lm = t >> 2, lk = (t & 3) << 3;
    floatx4 acc[4][4] = {};

    for (int k0 = 0; k0 < HIDDEN; k0 += BK) {
        *(uint4*)&As[lm][lk]      = *(const uint4*)(Aw + (size_t)(n0 + lm) * HIDDEN + k0 + lk);
        *(uint4*)&As[64 + lm][lk] = *(const uint4*)(Aw + (size_t)(n0 + 64 + lm) * HIDDEN + k0 + lk);
        *(uint4*)&Bs[lm][lk]      = *(const uint4*)(Bp + (size_t)(c0 + lm) * HIDDEN + k0 + lk);
        *(uint4*)&Bs[64 + lm][lk] = *(const uint4*)(Bp + (size_t)(c0 + 64 + lm) * HIDDEN + k0 + lk);
        __syncthreads();
        short8 aa[4], bb[4];
        #pragma unroll
        for (int i = 0; i < 4; ++i) {
            aa[i] = *(const short8*)&As[wm + i * 16 + fr][fk];
            bb[i] = *(const short8*)&Bs[wn + i * 16 + fr][fk];
        }
        #pragma unroll
        for (int i = 0; i < 4; ++i)
            #pragma unroll
            for (int j = 0; j < 4; ++j)
                acc[i][j] = mfma16(aa[i], bb[j], acc[i][j]);
        __syncthreads();
    }
    const int er = (lane >> 4) << 2, ec = lane & 15;
    #pragma unroll
    for (int i = 0; i < 4; ++i)
        #pragma unroll
        for (int j = 0; j < 4; ++j)
            #pragma unroll
            for (int r = 0; r < 4; ++r) {
                int grow = n0 + wm + i * 16 + er + r;   // gi-output row (gate dim)
                int kcol = c0 + wn + j * 16 + ec;       // k dim
                Cp[wf_index(grow, kcol)] = f2bf(acc[i][j][r]);
            }
}

// pack w_hh (f32 [1536][512]) into fragment-major bf16
__global__ void k_pack_hh(const float* __restrict__ whh, ushort* __restrict__ wfh) {
    int t = blockIdx.x * blockDim.x + threadIdx.x;   // 1536*64 threads
    if (t >= 3 * HIDDEN * HIDDEN / 8) return;
    int grow = t >> 6, k = (t & 63) << 3;
    const float* src = whh + (size_t)grow * HIDDEN + k;
    ushort o[8];
    #pragma unroll
    for (int j = 0; j < 8; ++j) o[j] = f2bf(src[j]);
    *(uint4*)(wfh + wf_index(grow, k)) = *(uint4*)o;   // j=0..7 contiguous -> 16B store
}

// ---- counting sort of edges by dst (once per call; graph shared by both layers) ----
__global__ void k_hist(const int* __restrict__ inputs, const int* __restrict__ A,
                       int* __restrict__ count) {
    bool is64 = idx_is64(inputs);
    int e = blockIdx.x * blockDim.x + threadIdx.x;
    if (e >= N_EDGES) return;
    int d = is64 ? A[2 * (N_EDGES + e)] : A[N_EDGES + e];
    if (d < 0 || d >= N_NODES) return;
    atomicAdd(count + d, 1);
}

#define SCAN_T 1024
__global__ __launch_bounds__(SCAN_T) void k_scan(const int* __restrict__ count,
                                                 int* __restrict__ row_start,
                                                 int* __restrict__ cursor) {
    __shared__ int part[SCAN_T];
    const int t = threadIdx.x;
    const int chunk = (N_NODES + SCAN_T - 1) / SCAN_T;   // 49
    const int base = t * chunk;
    int s = 0;
    for (int i = 0; i < chunk; ++i) {
        int idx = base + i;
        if (idx < N_NODES) s += count[idx];
    }
    part[t] = s;
    __syncthreads();
    for (int off = 1; off < SCAN_T; off <<= 1) {
        int add = (t >= off) ? part[t - off] : 0;
        __syncthreads();
        part[t] += add;
        __syncthreads();
    }
    int running = (t == 0) ? 0 : part[t - 1];
    for (int i = 0; i < chunk; ++i) {
        int idx = base + i;
        if (idx < N_NODES) {
            row_start[idx] = running;
            cursor[idx] = running;
            running += count[idx];
        }
    }
    if (t == 0) row_start[N_NODES] = part[SCAN_T - 1];
}

__global__ void k_place(const int* __restrict__ inputs, const int* __restrict__ A,
                        int* __restrict__ cursor, int* __restrict__ esrc) {
    bool is64 = idx_is64(inputs);
    int e = blockIdx.x * blockDim.x + threadIdx.x;
    if (e >= N_EDGES) return;
    int s, d;
    if (is64) { s = A[2 * e]; d = A[2 * (N_EDGES + e)]; }
    else      { s = A[e];     d = A[N_EDGES + e]; }
    if (s < 0 || s >= N_NODES || d < 0 || d >= N_NODES) return;
    int pos = atomicAdd(cursor + d, 1);
    esrc[pos] = s;
}

// ax[n] = sum_{e: dst=n} x[src[e]] : one wave per node, lane owns 8 cols, f32 acc -> bf16
__global__ __launch_bounds__(256) void k_agg(const int* __restrict__ row_start,
                                             const int* __restrict__ esrc,
                                             const ushort* __restrict__ x,
                                             ushort* __restrict__ ax) {
    int node = blockIdx.x * 4 + (threadIdx.x >> 6);
    if (node >= N_NODES) return;
    int lane = threadIdx.x & 63;
    int q = lane << 3;
    int beg = row_start[node], end = row_start[node + 1];
    float acc[8] = {};
    for (int i = beg; i < end; ++i) {
        int s = esrc[i];
        uint4 v = *(const uint4*)(x + (size_t)s * HIDDEN + q);
        const ushort* u = (const ushort*)&v;
        #pragma unroll
        for (int j = 0; j < 8; ++j) acc[j] += bf2f(u[j]);
    }
    ushort o[8];
    #pragma unroll
    for (int j = 0; j < 8; ++j) o[j] = f2bf(acc[j]);
    *(uint4*)(ax + (size_t)node * HIDDEN + q) = *(uint4*)o;
}

// Fused GRU v11: FREE-RUNNING WAVES -- zero barriers in the whole K-loop.
// v8-v10 post-mortem: per-phase s_barrier forces all 8 waves into lockstep convoy
// (everyone bursts LDS reads together while MFMA idles, then everyone MFMAs while
// LDS idles): phase cost = SUM of pipe demands, and 3 schedule variants all
// plateaued at 28% MfmaUtil. The barriers existed only for cross-wave sharing of
// staged fragments. v11 removes the sharing: each wave owns a PRIVATE 2x10KB LDS
// double buffer and stages its own operands (10 gld16/step), synchronized only by
// its own counted vmcnt(10) -- a per-wave counter needing no s_barrier. Waves skew
// freely, so one wave's MFMA overlaps another's LDS burst (sum -> max; m114: pipes
// co-schedule across waves). DMA->read same-wave ordering via vmcnt is safe.
// Geometry: 256 thr = 4 waves (2 row x 2 col), block 128r x 64c, wave 64r x 32c,
// K-step=16 (32 steps). Per step per wave: {10 gld16 (step s+1) -> vmcnt(10)
// (retires step-s loads, issued a FULL step ago) -> 10 asm ds_read -> lgkmcnt(0)+
// sched_barrier(0) -> setprio(1) -> 12 mfma32 -> setprio(0)}. Slots: 0-3 acts
// (av0,av1,xv0,xv1), 4-9 weights g0..g5. LDS 80KB/block -> 2 blocks/CU.
// Step 31 stages one garbage step into the dead buffer (sources advance at most
// ~1KB past bufA/bufB/weight ends -- all still inside the workspace; never used).
template<bool F32OUT>
__global__ __launch_bounds__(256, 2) void k_gru11(
    const ushort* __restrict__ agg, const ushort* __restrict__ xb_cur,
    const ushort* __restrict__ wfc,   // this layer's packed gi weights [3][16][32][64][8]
    const ushort* __restrict__ wfh,   // packed w_hh                  [3][16][32][64][8]
    const float* __restrict__ b_ih, const float* __restrict__ b_hh,
    ushort* __restrict__ outB, float* __restrict__ outF)
{
    __shared__ ushort S[4 * 10240];          // [wave][buf][slot 0..9][512] ushort, 80 KB
    const int x  = blockIdx.x & 7;           // XCD slot
    const int n  = blockIdx.x >> 3;
    const int by = n & 7;                    // col-block (64 cols)
    const int bx = x + ((n >> 3) << 3);      // row-block; 8 col-slices consecutive/XCD
    if (bx >= NBX) return;
    const int n0 = bx * 128;
    const int t = threadIdx.x, w = t >> 6, lane = t & 63;
    const int lrow = lane & 31, lhi = lane >> 5;
    const int wr = w >> 1, wc = w & 1;       // row-half 0/1, col-half 0/1
    const int wrow = wr << 6;                // 0 / 64
    const int cb = by * 2 + wc;              // 32-col block 0..15

    floatx16 a_sr[2] = {}, a_sz[2] = {}, a_in[2] = {}, a_hn[2] = {};

    const ushort* wB[6] = { wfc, wfc + 262144, wfc + 524288,    // gi r,z,n
                            wfh, wfh + 262144, wfh + 524288 };  // hh r,z,n

    // ---- wave-private staging descriptors: 10 frags per K16 step ----
    // slots 0-3: acts (agg rf0, agg rf1, x rf0, x rf1); 4-9: weights g0..g5.
    const ushort* sp[10];
    int           adv[10];
    {
        int r0 = n0 + wrow + lrow;       if (r0 >= N_NODES) r0 = N_NODES - 1;
        int r1 = n0 + wrow + 32 + lrow;  if (r1 >= N_NODES) r1 = N_NODES - 1;
        sp[0] = agg    + (size_t)r0 * HIDDEN + lhi * 8;  adv[0] = 16;
        sp[1] = agg    + (size_t)r1 * HIDDEN + lhi * 8;  adv[1] = 16;
        sp[2] = xb_cur + (size_t)r0 * HIDDEN + lhi * 8;  adv[2] = 16;
        sp[3] = xb_cur + (size_t)r1 * HIDDEN + lhi * 8;  adv[3] = 16;
        #pragma unroll
        for (int g = 0; g < 6; ++g) {
            sp[4 + g] = wB[g] + ((size_t)cb * 32) * 512 + (size_t)lane * 8;
            adv[4 + g] = 512;
        }
    }

    ushort* wS = S + (size_t)w * 10240;      // this wave's private region (2 x 5120)
    const uint ldsBase = (uint)(uintptr_t)(__attribute__((address_space(3))) ushort*)S;
    const uint wBase   = ldsBase + (uint)w * 20480u + (uint)lane * 16u;   // bytes

    // prologue: stage step 0 into private buf 0
    #pragma unroll
    for (int q = 0; q < 10; ++q) { gld16(sp[q], wS + q * 512); sp[q] += adv[q]; }

    for (int s = 0; s < 32; ++s) {
        const int cur = s & 1;
        // issue next step's 10 stages into the other private buffer (garbage at s=31)
        ushort* D = wS + (cur ^ 1) * 5120;
        #pragma unroll
        for (int q = 0; q < 10; ++q) { gld16(sp[q], D + q * 512); sp[q] += adv[q]; }
        // retire THIS step's 10 loads (issued a full step ago); newest 10 stay in flight
        asm volatile("s_waitcnt vmcnt(10)" ::: "memory");
        const uint a = wBase + (uint)cur * 10240u;
        short8 av0 = dsr<0>(a);
        short8 av1 = dsr<1024>(a);
        short8 xv0 = dsr<2048>(a);
        short8 xv1 = dsr<3072>(a);
        short8 W0  = dsr<4096>(a);
        short8 W1  = dsr<5120>(a);
        short8 W2  = dsr<6144>(a);
        short8 W3  = dsr<7168>(a);
        short8 W4  = dsr<8192>(a);
        short8 W5  = dsr<9216>(a);
        asm volatile("s_waitcnt lgkmcnt(0)" ::: "memory");
        __builtin_amdgcn_sched_barrier(0);
        __builtin_amdgcn_s_setprio(1);
        a_sr[0] = mfma32(av0, W0, a_sr[0]);  a_sr[1] = mfma32(av1, W0, a_sr[1]);
        a_sz[0] = mfma32(av0, W1, a_sz[0]);  a_sz[1] = mfma32(av1, W1, a_sz[1]);
        a_in[0] = mfma32(av0, W2, a_in[0]);  a_in[1] = mfma32(av1, W2, a_in[1]);
        a_sr[0] = mfma32(xv0, W3, a_sr[0]);  a_sr[1] = mfma32(xv1, W3, a_sr[1]);
        a_sz[0] = mfma32(xv0, W4, a_sz[0]);  a_sz[1] = mfma32(xv1, W4, a_sz[1]);
        a_hn[0] = mfma32(xv0, W5, a_hn[0]);  a_hn[1] = mfma32(xv1, W5, a_hn[1]);
        __builtin_amdgcn_s_setprio(0);
    }

    // epilogue: C/D map (32x32): col = lane&31, row = (reg&3) + 8*(reg>>2) + 4*(lane>>5)
    const int colL = (cb << 5) + lrow;
    const float bir = b_ih[colL] + b_hh[colL];
    const float biz = b_ih[HIDDEN + colL] + b_hh[HIDDEN + colL];
    const float bin = b_ih[2 * HIDDEN + colL];
    const float bhn = b_hh[2 * HIDDEN + colL];
    #pragma unroll
    for (int rf = 0; rf < 2; ++rf) {
        #pragma unroll
        for (int rg = 0; rg < 16; ++rg) {
            const int row = n0 + wrow + rf * 32 + (rg & 3) + ((rg >> 2) << 3) + (lhi << 2);
            if (row >= N_NODES) continue;
            float vsr = a_sr[rf][rg] + bir;
            float vsz = a_sz[rf][rg] + biz;
            float vin = a_in[rf][rg] + bin;
            float vhn = a_hn[rf][rg] + bhn;
            float rr = 1.f / (1.f + __expf(-vsr));
            float zz = 1.f / (1.f + __expf(-vsz));
            float nn = tanhf(vin + rr * vhn);
            float h  = bf2f(xb_cur[(size_t)row * HIDDEN + colL]);
            float out = (1.f - zz) * nn + zz * h;
            if (F32OUT) outF[(size_t)row * HIDDEN + colL] = out;
            else        outB[(size_t)row * HIDDEN + colL] = f2bf(out);
        }
    }
}

extern "C" void kernel_launch(void* const* d_in, const int* in_sizes, int n_in,
                              void* d_out, int out_size, void* d_ws, size_t ws_size,
                              hipStream_t stream) {
    const int*   inputs = (const int*)d_in[0];
    const int*   A      = (const int*)d_in[1];
    const float* emb    = (const float*)d_in[2];
    const float* weight = (const float*)d_in[3];
    const float* w_ih   = (const float*)d_in[4];
    const float* w_hh   = (const float*)d_in[5];
    const float* b_ih   = (const float*)d_in[6];
    const float* b_hh   = (const float*)d_in[7];

    // ws: WihB 1.6 + Wb 1.05 + WFc 3.1 + WFhh 1.6 + bufA 51.2 + bufB 51.2 + sort 1.4 ≈ 111 MB
    // ax for layer 0 lives in d_out (51.2 of 102.4 MB); layer 1 ax reuses bufA.
    char* ws = (char*)d_ws;
    size_t off = 0;
    auto alloc = [&](size_t bytes) { void* p = ws + off; off += (bytes + 255) & ~255ull; return p; };
    ushort* WihB      = (ushort*)alloc((size_t)3 * HIDDEN * HIDDEN * sizeof(ushort));
    ushort* Wb        = (ushort*)alloc((size_t)2 * HIDDEN * HIDDEN * sizeof(ushort));
    ushort* WFc       = (ushort*)alloc((size_t)2 * 3 * HIDDEN * HIDDEN * sizeof(ushort));
    ushort* WFhh      = (ushort*)alloc((size_t)3 * HIDDEN * HIDDEN * sizeof(ushort));
    ushort* bufA      = (ushort*)alloc((size_t)N_NODES * HIDDEN * sizeof(ushort));
    ushort* bufB      = (ushort*)alloc((size_t)N_NODES * HIDDEN * sizeof(ushort));
    int*    count     = (int*)alloc((size_t)N_NODES * sizeof(int));
    int*    row_start = (int*)alloc((size_t)(N_NODES + 1) * sizeof(int));
    int*    cursor    = (int*)alloc((size_t)N_NODES * sizeof(int));
    int*    esrc      = (int*)alloc((size_t)N_EDGES * sizeof(int));
    ushort* ax0       = (ushort*)d_out;

    const int nW3 = 3 * HIDDEN * HIDDEN, nW2 = 2 * HIDDEN * HIDDEN;
    const size_t WF_L = (size_t)3 * HIDDEN * HIDDEN;   // per-layer packed-weight stride

    k_cvt8<<<(nW3 / 8 + 255) / 256, 256, 0, stream>>>(w_ih, WihB, nW3);
    k_cvt8<<<(nW2 / 8 + 255) / 256, 256, 0, stream>>>(weight, Wb, nW2);
    k_pack_hh<<<(nW3 / 8 + 255) / 256, 256, 0, stream>>>(w_hh, WFhh);
    k_gemm_w<<<dim3(12, 4, 2), 256, 0, stream>>>(WihB, Wb, WFc);   // frag-major Wc

    k_gather<<<(N_NODES * 64 + 255) / 256, 256, 0, stream>>>(inputs, emb, bufA);

    hipMemsetAsync(count, 0, (size_t)N_NODES * sizeof(int), stream);
    k_hist<<<(N_EDGES + 255) / 256, 256, 0, stream>>>(inputs, A, count);
    k_scan<<<1, SCAN_T, 0, stream>>>(count, row_start, cursor);
    k_place<<<(N_EDGES + 255) / 256, 256, 0, stream>>>(inputs, A, cursor, esrc);

    dim3 gGru(8 * 8 * ((NBX + 7) / 8));   // x(=XCD) * by(8) * row-groups
    dim3 ga((N_NODES + 3) / 4);

    // Layer 0: ax0 = segsum(x0) -> d_out region; GRU(ax0, x0=bufA) -> bufB
    k_agg<<<ga, 256, 0, stream>>>(row_start, esrc, bufA, ax0);
    k_gru11<false><<<gGru, 256, 0, stream>>>(ax0, bufA, WFc, WFhh, b_ih, b_hh, bufB, nullptr);

    // Layer 1: ax1 = segsum(x1) -> bufA (x0 dead); GRU(ax1, x1=bufB) -> f32 d_out
    k_agg<<<ga, 256, 0, stream>>>(row_start, esrc, bufB, bufA);
    k_gru11<true><<<gGru, 256, 0, stream>>>(bufA, bufB, WFc + WF_L, WFhh, b_ih, b_hh,
                                            nullptr, (float*)d_out);
}